// Round 13
// baseline (316.762 us; speedup 1.0000x reference)
//
#include <hip/hip_runtime.h>
#include <math.h>

#define F 64
#define NPB 160        // nodes per bucket

typedef __attribute__((ext_vector_type(8))) short bf16x8;
typedef __attribute__((ext_vector_type(4))) float f32x4;

__device__ inline unsigned short f2bf(float f) {
  unsigned int u = __float_as_uint(f);
  u += 0x7fffu + ((u >> 16) & 1u);   // round-to-nearest-even
  return (unsigned short)(u >> 16);
}

// ---------------- MFMA GEMM body (shared) ----------------
// PACKED: Wsrc is pre-packed uint4 fragments; else raw fp32 W (strided prologue).
template<bool IN_BF16, bool PACKED>
__device__ __forceinline__ void gemm_body(const void* __restrict__ in, const void* __restrict__ Wsrc,
                                          const float* __restrict__ avs, const float* __restrict__ avd,
                                          unsigned short* __restrict__ hgb, float* __restrict__ als,
                                          float* __restrict__ ald, int n, int bid, int nbl) {
  int tid = threadIdx.x, lane = tid & 63, wv = tid >> 6;
  int l15 = lane & 15, quad = lane >> 4;
  bf16x8 bfr[4][2];
  if constexpr (PACKED) {
    const uint4* wf = (const uint4*)Wsrc;
    #pragma unroll
    for (int cb = 0; cb < 8; cb++) {
      uint4 u = wf[cb * 64 + lane];
      bfr[cb >> 1][cb & 1] = *(const bf16x8*)&u;
    }
  } else {
    const float* W = (const float*)Wsrc;
    #pragma unroll
    for (int c = 0; c < 4; c++)
      #pragma unroll
      for (int kk = 0; kk < 2; kk++)
        #pragma unroll
        for (int j = 0; j < 8; j++) {
          int kd = kk * 32 + quad * 8 + j;
          bfr[c][kk][j] = (short)f2bf(W[kd * F + c * 16 + l15]);
        }
  }
  float as_l[4], ad_l[4];
  #pragma unroll
  for (int c = 0; c < 4; c++) { as_l[c] = avs[c * 16 + l15]; ad_l[c] = avd[c * 16 + l15]; }

  int nchunks = n >> 6;
  for (int chunk = bid; chunk < nchunks; chunk += nbl) {
    int r0 = (chunk << 6) + (wv << 4);
    bf16x8 a0, a1;
    if constexpr (IN_BF16) {
      const uint4* row4 = (const uint4*)((const unsigned short*)in + (size_t)(r0 + l15) * F);
      uint4 u0 = row4[quad];
      uint4 u1 = row4[quad + 4];
      a0 = *(const bf16x8*)&u0;
      a1 = *(const bf16x8*)&u1;
    } else {
      const float4* xr = (const float4*)((const float*)in + (size_t)(r0 + l15) * F + quad * 8);
      float4 xa = xr[0], xb = xr[1];
      float4 xc = xr[8], xd = xr[9];
      a0[0] = (short)f2bf(xa.x); a0[1] = (short)f2bf(xa.y); a0[2] = (short)f2bf(xa.z); a0[3] = (short)f2bf(xa.w);
      a0[4] = (short)f2bf(xb.x); a0[5] = (short)f2bf(xb.y); a0[6] = (short)f2bf(xb.z); a0[7] = (short)f2bf(xb.w);
      a1[0] = (short)f2bf(xc.x); a1[1] = (short)f2bf(xc.y); a1[2] = (short)f2bf(xc.z); a1[3] = (short)f2bf(xc.w);
      a1[4] = (short)f2bf(xd.x); a1[5] = (short)f2bf(xd.y); a1[6] = (short)f2bf(xd.z); a1[7] = (short)f2bf(xd.w);
    }
    f32x4 cfr[4];
    #pragma unroll
    for (int c = 0; c < 4; c++) {
      cfr[c] = (f32x4){0.f, 0.f, 0.f, 0.f};
      cfr[c] = __builtin_amdgcn_mfma_f32_16x16x32_bf16(a0, bfr[c][0], cfr[c], 0, 0, 0);
      cfr[c] = __builtin_amdgcn_mfma_f32_16x16x32_bf16(a1, bfr[c][1], cfr[c], 0, 0, 0);
    }
    #pragma unroll
    for (int i = 0; i < 4; i++) {
      int row = r0 + quad * 4 + i;
      #pragma unroll
      for (int c = 0; c < 4; c++) hgb[(size_t)row * F + c * 16 + l15] = f2bf(cfr[c][i]);
      float ps = cfr[0][i] * as_l[0] + cfr[1][i] * as_l[1] + cfr[2][i] * as_l[2] + cfr[3][i] * as_l[3];
      float pd = cfr[0][i] * ad_l[0] + cfr[1][i] * ad_l[1] + cfr[2][i] * ad_l[2] + cfr[3][i] * ad_l[3];
      #pragma unroll
      for (int o = 1; o <= 8; o <<= 1) { ps += __shfl_xor(ps, o); pd += __shfl_xor(pd, o); }
      if (l15 == 0) { als[row] = ps; ald[row] = pd; }
    }
  }
}

// ---------------- fused: block-local bucket sort (blocks < nblk) + layer-1 GEMM ----------------
// Sort: per block, 2-pass — LDS histogram of its CH edges, LDS prefix, then scatter bucket-ordered
// into the block's PRIVATE contiguous region binned[k*ch ...] (sequential full-line writes).
// Emits cntT (b-major, for global scan) and lstart[k*1024+b] (local bin offsets, coalesced).
__global__ __launch_bounds__(256) void k_sort_gemm1(const int* __restrict__ esrc, const int* __restrict__ edst,
                                                    int* __restrict__ cntT, int* __restrict__ lstart,
                                                    unsigned int* __restrict__ binned,
                                                    int e, int ch, int nblk, int nb,
                                                    const float* __restrict__ x, const float* __restrict__ W1,
                                                    const float* __restrict__ avs, const float* __restrict__ avd,
                                                    unsigned short* __restrict__ hgb, float* __restrict__ als,
                                                    float* __restrict__ ald, int n) {
  int k = blockIdx.x, tid = threadIdx.x;
  if (k >= nblk) {
    gemm_body<false, false>(x, W1, avs, avd, hgb, als, ald, n, k - nblk, (int)gridDim.x - nblk);
    return;
  }
  __shared__ int h[1024];
  __shared__ int cur[1024];
  __shared__ int sc[256];
  for (int i = tid; i < 1024; i += 256) h[i] = 0;
  __syncthreads();
  int beg = k * ch, end = min(e, beg + ch);
  for (int i = beg + tid; i < end; i += 256) atomicAdd(&h[edst[i] / NPB], 1);
  __syncthreads();
  // exclusive prefix over 1024 bins: 4 bins/thread + block scan
  int s0 = h[tid * 4], s1 = h[tid * 4 + 1], s2 = h[tid * 4 + 2], s3 = h[tid * 4 + 3];
  int tot = s0 + s1 + s2 + s3;
  sc[tid] = tot;
  __syncthreads();
  #pragma unroll
  for (int o = 1; o < 256; o <<= 1) {
    int y = (tid >= o) ? sc[tid - o] : 0;
    __syncthreads();
    sc[tid] += y;
    __syncthreads();
  }
  int base = sc[tid] - tot;   // exclusive
  int e0 = base, e1 = base + s0, e2 = e1 + s1, e3 = e2 + s2;
  cur[tid * 4] = beg + e0; cur[tid * 4 + 1] = beg + e1;
  cur[tid * 4 + 2] = beg + e2; cur[tid * 4 + 3] = beg + e3;
  int4 ls = make_int4(e0, e1, e2, e3);
  *(int4*)&lstart[k * 1024 + tid * 4] = ls;
  if (tid * 4 + 0 < nb) cntT[(tid * 4 + 0) * nblk + k] = s0;
  if (tid * 4 + 1 < nb) cntT[(tid * 4 + 1) * nblk + k] = s1;
  if (tid * 4 + 2 < nb) cntT[(tid * 4 + 2) * nblk + k] = s2;
  if (tid * 4 + 3 < nb) cntT[(tid * 4 + 3) * nblk + k] = s3;
  __syncthreads();
  for (int i = beg + tid; i < end; i += 256) {
    int d = edst[i];
    int b = d / NPB;
    unsigned int ld = (unsigned int)(d - b * NPB);
    int p = atomicAdd(&cur[b], 1);
    binned[p] = (unsigned int)esrc[i] | (ld << 24);
  }
}

// per-256-block exclusive scan of cntT; extra last block packs W2 fragments
__global__ __launch_bounds__(256) void k_scan1(const int* __restrict__ counts, int* __restrict__ offs,
                                               int* __restrict__ bsums, int n,
                                               const float* __restrict__ W2, uint4* __restrict__ wf) {
  int tid = threadIdx.x;
  if (blockIdx.x == gridDim.x - 1) {
    for (int i = tid; i < 512; i += 256) {
      int cb = i >> 6, lane = i & 63;
      int c = cb >> 1, kk = cb & 1;
      int l15 = lane & 15, quad = lane >> 4;
      unsigned short p[8];
      #pragma unroll
      for (int j = 0; j < 8; j++) {
        int kd = kk * 32 + quad * 8 + j;
        p[j] = f2bf(W2[kd * F + c * 16 + l15]);
      }
      wf[i] = *(const uint4*)p;
    }
    return;
  }
  int lane = tid & 63, wv = tid >> 6;
  int i = blockIdx.x * 256 + tid;
  int v = (i < n) ? counts[i] : 0;
  int x = v;
  #pragma unroll
  for (int o = 1; o <= 32; o <<= 1) { int y = __shfl_up(x, o); if (lane >= o) x += y; }
  __shared__ int wsum[4];
  if (lane == 63) wsum[wv] = x;
  __syncthreads();
  int add = 0;
  for (int w = 0; w < wv; w++) add += wsum[w];
  int incl = x + add;
  if (i < n) offs[i] = incl - v;
  if (tid == 255) bsums[blockIdx.x] = incl;
}

// single-block scan of block sums; also initializes out[] = b_out
__global__ __launch_bounds__(256) void k_scan2(int* __restrict__ bs, int nb,
                                               float* __restrict__ out, const float* __restrict__ bo, int ng) {
  __shared__ int wsum[4];
  __shared__ int carry_sh;
  int tid = threadIdx.x, lane = tid & 63, wv = tid >> 6;
  float b0 = bo[0];
  for (int i = tid; i < ng; i += 256) out[i] = b0;
  if (tid == 0) carry_sh = 0;
  __syncthreads();
  for (int base = 0; base < nb; base += 256) {
    int i = base + tid;
    int v = (i < nb) ? bs[i] : 0;
    int x = v;
    #pragma unroll
    for (int o = 1; o <= 32; o <<= 1) { int y = __shfl_up(x, o); if (lane >= o) x += y; }
    if (lane == 63) wsum[wv] = x;
    __syncthreads();
    int add = 0;
    for (int w = 0; w < wv; w++) add += wsum[w];
    int incl = x + add;
    int carry = carry_sh;
    if (i < nb) bs[i] = incl - v + carry;
    __syncthreads();
    if (tid == 255) carry_sh = carry + incl;
    __syncthreads();
  }
}

// one block per bucket: gather the bucket's 256 runs, build CSR rows (self-loop at head)
__global__ __launch_bounds__(256) void k_bucket_csr(const unsigned int* __restrict__ binned,
                                                    const int* __restrict__ posT, const int* __restrict__ bsums,
                                                    const int* __restrict__ cntT, const int* __restrict__ lstart,
                                                    int* __restrict__ ssrc, int* __restrict__ offs,
                                                    int n, int nblk, int nb, int e, int ch) {
  __shared__ int ncnt[NPB];
  __shared__ int cur[NPB];
  __shared__ int sc[256];
  __shared__ int runbase[256];
  __shared__ int runlen[256];
  int b = blockIdx.x, tid = threadIdx.x;
  int node0 = b * NPB;
  int nn = min(NPB, n - node0);
  int i0 = b * nblk;
  int ebeg = posT[i0] + bsums[i0 >> 8];
  runlen[tid] = cntT[i0 + tid];
  runbase[tid] = tid * ch + lstart[tid * 1024 + b];
  for (int i = tid; i < NPB; i += 256) ncnt[i] = 0;
  __syncthreads();
  {
    int len = runlen[tid], base = runbase[tid];
    for (int j = 0; j < len; j++) { unsigned int v = binned[base + j]; atomicAdd(&ncnt[v >> 24], 1); }
  }
  __syncthreads();
  int x = (tid < nn) ? ncnt[tid] + 1 : 0;   // +1 self-loop
  sc[tid] = x;
  __syncthreads();
  #pragma unroll
  for (int o = 1; o < 256; o <<= 1) {
    int y = (tid >= o) ? sc[tid - o] : 0;
    __syncthreads();
    sc[tid] += y;
    __syncthreads();
  }
  int noff = sc[tid] - x;
  int outbase = ebeg + node0;
  if (tid < nn) {
    cur[tid] = noff + 1;
    offs[node0 + tid] = outbase + noff;
    ssrc[outbase + noff] = node0 + tid;    // self-loop at row head
  }
  __syncthreads();
  {
    int len = runlen[tid], base = runbase[tid];
    for (int j = 0; j < len; j++) {
      unsigned int v = binned[base + j];
      int p = atomicAdd(&cur[v >> 24], 1);
      ssrc[outbase + p] = (int)(v & 0xFFFFFFu);
    }
  }
  if (b == 0 && tid == 0) offs[n] = e + n;
}

__global__ __launch_bounds__(256) void k_gemm2(const unsigned short* __restrict__ in, const uint4* __restrict__ wf,
                                               const float* __restrict__ avs, const float* __restrict__ avd,
                                               unsigned short* __restrict__ hgb, float* __restrict__ als,
                                               float* __restrict__ ald, int n) {
  gemm_body<true, true>(in, wf, avs, avd, hgb, als, ald, n, blockIdx.x, gridDim.x);
}

// ---------------- fused softmax+SpMM, node-per-subgroup ----------------
// MODE 0: write bf16 rows (layer 1).
// MODE 1: fused readout — per-node dot with Wout, LDS-aggregated per block (<=3 groups), <=3 global atomics.
template<int MODE>
__global__ __launch_bounds__(256) void k_spmm(const int* __restrict__ offs, const int* __restrict__ ssrc,
                                              const unsigned short* __restrict__ hgb,
                                              const float* __restrict__ als, const float* __restrict__ ald,
                                              const float* __restrict__ bias, const float* __restrict__ Wout,
                                              void* __restrict__ outp, int n) {
  int tid = threadIdx.x, lane = tid & 63, wv = tid >> 6;
  int g8 = lane >> 3, l8 = lane & 7;
  const uint4* hg4 = (const uint4*)hgb;
  float4 bl0 = ((const float4*)bias)[l8 * 2];
  float4 bl1 = ((const float4*)bias)[l8 * 2 + 1];

  __shared__ float gsl[3];   // MODE 1 group partials
  if (MODE == 1 && tid < 3) gsl[tid] = 0.f;

  int node = (blockIdx.x * 4 + wv) * 8 + g8;
  int cnode = min(node, n - 1);
  bool nodeok = node < n;
  int beg = offs[cnode];
  int deg = nodeok ? (offs[cnode + 1] - beg) : 0;
  int degc = max(deg - 1, 0);
  float aldv = ald[cnode];

  int dm = deg;
  #pragma unroll
  for (int o = 8; o <= 32; o <<= 1) dm = max(dm, __shfl_xor(dm, o));

  float s = 0.f;
  float acc[8];
  #pragma unroll
  for (int k = 0; k < 8; k++) acc[k] = 0.f;

  #pragma unroll 2
  for (int j = 0; j < dm; j++) {
    int jj = min(j, degc);
    int src = ssrc[beg + jj];
    float t = als[src] + aldv;
    t = fmaxf(t, 0.2f * t);                   // leaky_relu 0.2
    float ex = (j < deg) ? __expf(t) : 0.f;
    s += ex;
    uint4 u = hg4[(size_t)src * 8 + l8];
    acc[0] = fmaf(ex, __uint_as_float(u.x << 16), acc[0]);
    acc[1] = fmaf(ex, __uint_as_float(u.x & 0xffff0000u), acc[1]);
    acc[2] = fmaf(ex, __uint_as_float(u.y << 16), acc[2]);
    acc[3] = fmaf(ex, __uint_as_float(u.y & 0xffff0000u), acc[3]);
    acc[4] = fmaf(ex, __uint_as_float(u.z << 16), acc[4]);
    acc[5] = fmaf(ex, __uint_as_float(u.z & 0xffff0000u), acc[5]);
    acc[6] = fmaf(ex, __uint_as_float(u.w << 16), acc[6]);
    acc[7] = fmaf(ex, __uint_as_float(u.w & 0xffff0000u), acc[7]);
  }

  float iv = 1.f / (s + 1e-16f);
  float r[8];
  r[0] = fmaxf(fmaf(acc[0], iv, bl0.x), 0.f);
  r[1] = fmaxf(fmaf(acc[1], iv, bl0.y), 0.f);
  r[2] = fmaxf(fmaf(acc[2], iv, bl0.z), 0.f);
  r[3] = fmaxf(fmaf(acc[3], iv, bl0.w), 0.f);
  r[4] = fmaxf(fmaf(acc[4], iv, bl1.x), 0.f);
  r[5] = fmaxf(fmaf(acc[5], iv, bl1.y), 0.f);
  r[6] = fmaxf(fmaf(acc[6], iv, bl1.z), 0.f);
  r[7] = fmaxf(fmaf(acc[7], iv, bl1.w), 0.f);

  if constexpr (MODE == 0) {
    if (!nodeok) return;
    unsigned short p[8];
    #pragma unroll
    for (int k = 0; k < 8; k++) p[k] = f2bf(r[k]);
    ((uint4*)outp)[(size_t)node * 8 + l8] = *(const uint4*)p;
  } else {
    int node0 = blockIdx.x * 32;
    int grp0 = node0 / 20;
    int grp = cnode / 20, slot = cnode - grp * 20;
    const float* wr = Wout + slot * F + l8 * 8;
    float dot = 0.f;
    #pragma unroll
    for (int k = 0; k < 8; k++) dot = fmaf(r[k], wr[k], dot);
    #pragma unroll
    for (int o = 1; o <= 4; o <<= 1) dot += __shfl_xor(dot, o);  // within subgroup
    __syncthreads();                       // gsl init visible
    if (nodeok && l8 == 0) atomicAdd(&gsl[grp - grp0], dot);
    __syncthreads();
    if (tid < 3) {
      float v = gsl[tid];
      if (v != 0.f) atomicAdd((float*)outp + grp0 + tid, v);
    }
  }
}

// ---------------- launch ----------------
extern "C" void kernel_launch(void* const* d_in, const int* in_sizes, int n_in,
                              void* d_out, int out_size, void* d_ws, size_t ws_size,
                              hipStream_t stream) {
  const float* x   = (const float*)d_in[0];
  const int*   ei  = (const int*)d_in[1];
  const float* W1  = (const float*)d_in[2];
  const float* as1 = (const float*)d_in[3];
  const float* ad1 = (const float*)d_in[4];
  const float* b1  = (const float*)d_in[5];
  const float* W2  = (const float*)d_in[6];
  const float* as2 = (const float*)d_in[7];
  const float* ad2 = (const float*)d_in[8];
  const float* b2  = (const float*)d_in[9];
  const float* Wo  = (const float*)d_in[10];
  const float* bo  = (const float*)d_in[11];
  float* out = (float*)d_out;

  const int N = in_sizes[0] / F;
  const int E = in_sizes[1] / 2;
  const int* esrc = ei;
  const int* edst = ei + E;

  size_t off = 0;
  auto alloc = [&](size_t bytes) -> void* {
    void* p = (char*)d_ws + off;
    off += (bytes + 255) & ~(size_t)255;
    return p;
  };
  float* A    = (float*)alloc((size_t)N * F * 4);           // A1 bf16; CSR scratch aliases (dead until spmm<0>)
  unsigned short* hgb = (unsigned short*)alloc((size_t)N * F * 2);  // bf16 gemm outputs
  float* als  = (float*)alloc((size_t)N * 4);
  float* ald  = (float*)alloc((size_t)N * 4);
  int* offs   = (int*)alloc((size_t)(N + 1) * 4);
  int* bsums  = (int*)alloc(8192);
  int* ssrc   = (int*)alloc((size_t)(E + N) * 4);           // CSR src lists
  uint4* wf   = (uint4*)alloc(8192);                        // packed W2 frags: 512 uint4
  (void)ws_size; (void)n_in; (void)out_size;

  const int NBLK = 256;
  const int NB = (N + NPB - 1) / NPB;           // 1024 buckets
  const int CH = (E + NBLK - 1) / NBLK;         // edges per sort block
  const int FLAT = NB * NBLK;

  // CSR scratch inside A (binned must NOT alias hgb — gemm1 writes hgb concurrently)
  int* cntT            = (int*)A;                                        // 1 MB
  int* posT            = (int*)((char*)A + (size_t)2 * 1024 * 1024);     // 1 MB
  int* lstart          = (int*)((char*)A + (size_t)4 * 1024 * 1024);     // 1 MB (256 x 1024)
  unsigned int* binned = (unsigned int*)((char*)A + (size_t)6 * 1024 * 1024);  // E x 4 B

  int gF = (FLAT + 255) / 256;
  int NG = N / 20;

  // fused: block-local bucket sort (256 blocks) + layer-1 GEMM (2560 blocks)
  k_sort_gemm1<<<NBLK + (N >> 6), 256, 0, stream>>>(esrc, edst, cntT, lstart, binned, E, CH, NBLK, NB,
                                                    x, W1, as1, ad1, hgb, als, ald, N);
  // global scan (+ W2 fragment pack in extra block) and out init
  k_scan1<<<gF + 1, 256, 0, stream>>>(cntT, posT, bsums, FLAT, W2, wf);
  k_scan2<<<1, 256, 0, stream>>>(bsums, gF, out, bo, NG);
  // CSR assembly from per-block runs
  k_bucket_csr<<<NB, 256, 0, stream>>>(binned, posT, bsums, cntT, lstart, ssrc, offs, N, NBLK, NB, E, CH);

  int gSp = (N + 31) / 32;
  // layer 1 aggregation -> bf16 A1
  k_spmm<0><<<gSp, 256, 0, stream>>>(offs, ssrc, hgb, als, ald, b1, nullptr, A, N);
  // layer 2 GEMM (reads bf16 A1)
  k_gemm2<<<(N >> 6), 256, 0, stream>>>((const unsigned short*)A, wf, as2, ad2, hgb, als, ald, N);
  // layer 2 aggregation + fused readout
  k_spmm<1><<<gSp, 256, 0, stream>>>(offs, ssrc, hgb, als, ald, b2, Wo, out, N);
}